// Round 3
// baseline (1769.067 us; speedup 1.0000x reference)
//
#include <hip/hip_runtime.h>
#include <math.h>

#define Bb 2
#define Ss 2048
#define Dd 1024
#define Hh 16
#define HDd 64
#define KSEL 1024           // k = S * (1 - 0.5)
#define MROWS 4096          // B*S

__device__ __forceinline__ unsigned f2u(float f) {
    unsigned u = __float_as_uint(f);
    return (u & 0x80000000u) ? ~u : (u | 0x80000000u);
}

// ---------------------------------------------------------------------------
// GEMM body: C(128x128) tile of  Y = X @ W^T (+bias), X: Mx1024, W: 1024x1024
// 256 threads, 8x8 microtile. TRANSPOSED=1 writes Y as [B][H][S][HD].
// ---------------------------------------------------------------------------
template <int TRANSPOSED>
__device__ __forceinline__ void gemm_body_1024(const float* __restrict__ X,
                                               const float* __restrict__ W,
                                               const float* __restrict__ bias,
                                               float* __restrict__ Y,
                                               int m0, int n0) {
    const int tid = threadIdx.x;
    const int tx = tid & 15, ty = tid >> 4;

    __shared__ __align__(16) float As[16][128];
    __shared__ __align__(16) float Bs[16][128];

    float acc[8][8];
#pragma unroll
    for (int i = 0; i < 8; ++i)
#pragma unroll
        for (int j = 0; j < 8; ++j) acc[i][j] = 0.f;

    for (int k0 = 0; k0 < 1024; k0 += 16) {
#pragma unroll
        for (int c = 0; c < 2; ++c) {
            int idx = tid + c * 256;
            int row = idx >> 2;
            int kq  = (idx & 3) << 2;
            float4 va = *(const float4*)&X[(size_t)(m0 + row) * 1024 + k0 + kq];
            As[kq + 0][row] = va.x; As[kq + 1][row] = va.y;
            As[kq + 2][row] = va.z; As[kq + 3][row] = va.w;
            float4 vb = *(const float4*)&W[(size_t)(n0 + row) * 1024 + k0 + kq];
            Bs[kq + 0][row] = vb.x; Bs[kq + 1][row] = vb.y;
            Bs[kq + 2][row] = vb.z; Bs[kq + 3][row] = vb.w;
        }
        __syncthreads();
#pragma unroll
        for (int kk = 0; kk < 16; ++kk) {
            float a[8], b[8];
            *(float4*)&a[0] = *(const float4*)&As[kk][ty * 4];
            *(float4*)&a[4] = *(const float4*)&As[kk][64 + ty * 4];
            *(float4*)&b[0] = *(const float4*)&Bs[kk][tx * 4];
            *(float4*)&b[4] = *(const float4*)&Bs[kk][64 + tx * 4];
#pragma unroll
            for (int i = 0; i < 8; ++i)
#pragma unroll
                for (int j = 0; j < 8; ++j) acc[i][j] = fmaf(a[i], b[j], acc[i][j]);
        }
        __syncthreads();
    }

#pragma unroll
    for (int i = 0; i < 8; ++i) {
        int m = m0 + ((i < 4) ? (ty * 4 + i) : (64 + ty * 4 + i - 4));
#pragma unroll
        for (int jq = 0; jq < 2; ++jq) {
            int n = n0 + jq * 64 + tx * 4;
            float4 bv = *(const float4*)&bias[n];
            float4 v;
            v.x = acc[i][jq * 4 + 0] + bv.x;
            v.y = acc[i][jq * 4 + 1] + bv.y;
            v.z = acc[i][jq * 4 + 2] + bv.z;
            v.w = acc[i][jq * 4 + 3] + bv.w;
            if (TRANSPOSED) {
                int bi = m >> 11, s = m & 2047;
                int h = n >> 6, d = n & 63;
                *(float4*)&Y[(((size_t)(bi * Hh + h)) * Ss + s) * HDd + d] = v;
            } else {
                *(float4*)&Y[(size_t)m * 1024 + n] = v;
            }
        }
    }
}

// QKV fused: grid (N/128=8, M/128=32, 3)
__global__ __launch_bounds__(256) void qkv_kernel(
    const float* __restrict__ q, const float* __restrict__ k, const float* __restrict__ v,
    const float* __restrict__ Wq, const float* __restrict__ Wk, const float* __restrict__ Wv,
    const float* __restrict__ bq, const float* __restrict__ bk, const float* __restrict__ bv,
    float* __restrict__ Qo, float* __restrict__ Ko, float* __restrict__ Vo) {
    int z = blockIdx.z;
    const float* X = (z == 0) ? q : ((z == 1) ? k : v);
    const float* W = (z == 0) ? Wq : ((z == 1) ? Wk : Wv);
    const float* bias = (z == 0) ? bq : ((z == 1) ? bk : bv);
    float* Y = (z == 0) ? Qo : ((z == 1) ? Ko : Vo);
    gemm_body_1024<1>(X, W, bias, Y, blockIdx.y * 128, blockIdx.x * 128);
}

// out = O @ Wo^T + bo : grid (8, 32)
__global__ __launch_bounds__(256) void outproj_kernel(
    const float* __restrict__ O, const float* __restrict__ Wo,
    const float* __restrict__ bo, float* __restrict__ Y) {
    gemm_body_1024<0>(O, Wo, bo, Y, blockIdx.y * 128, blockIdx.x * 128);
}

// ---------------------------------------------------------------------------
// scores = Q_bh @ K_bh^T * 0.125 : grid (16, 16, 32), K-dim = 64
// ---------------------------------------------------------------------------
__global__ __launch_bounds__(256) void scores_kernel(const float* __restrict__ Q,
                                                     const float* __restrict__ Kd,
                                                     float* __restrict__ Sc) {
    const int tid = threadIdx.x;
    const int tx = tid & 15, ty = tid >> 4;
    const int z = blockIdx.z;
    const int m0 = blockIdx.y * 128;
    const int n0 = blockIdx.x * 128;
    const float* Qz = Q + (size_t)z * Ss * HDd;
    const float* Kz = Kd + (size_t)z * Ss * HDd;
    float* Cz = Sc + (size_t)z * Ss * Ss;

    __shared__ __align__(16) float As[16][128];
    __shared__ __align__(16) float Bs[16][128];

    float acc[8][8];
#pragma unroll
    for (int i = 0; i < 8; ++i)
#pragma unroll
        for (int j = 0; j < 8; ++j) acc[i][j] = 0.f;

    for (int k0 = 0; k0 < 64; k0 += 16) {
#pragma unroll
        for (int c = 0; c < 2; ++c) {
            int idx = tid + c * 256;
            int row = idx >> 2;
            int kq  = (idx & 3) << 2;
            float4 va = *(const float4*)&Qz[(size_t)(m0 + row) * 64 + k0 + kq];
            As[kq + 0][row] = va.x; As[kq + 1][row] = va.y;
            As[kq + 2][row] = va.z; As[kq + 3][row] = va.w;
            float4 vb = *(const float4*)&Kz[(size_t)(n0 + row) * 64 + k0 + kq];
            Bs[kq + 0][row] = vb.x; Bs[kq + 1][row] = vb.y;
            Bs[kq + 2][row] = vb.z; Bs[kq + 3][row] = vb.w;
        }
        __syncthreads();
#pragma unroll
        for (int kk = 0; kk < 16; ++kk) {
            float a[8], b[8];
            *(float4*)&a[0] = *(const float4*)&As[kk][ty * 4];
            *(float4*)&a[4] = *(const float4*)&As[kk][64 + ty * 4];
            *(float4*)&b[0] = *(const float4*)&Bs[kk][tx * 4];
            *(float4*)&b[4] = *(const float4*)&Bs[kk][64 + tx * 4];
#pragma unroll
            for (int i = 0; i < 8; ++i)
#pragma unroll
                for (int j = 0; j < 8; ++j) acc[i][j] = fmaf(a[i], b[j], acc[i][j]);
        }
        __syncthreads();
    }

#pragma unroll
    for (int i = 0; i < 8; ++i) {
        int m = m0 + ((i < 4) ? (ty * 4 + i) : (64 + ty * 4 + i - 4));
#pragma unroll
        for (int jq = 0; jq < 2; ++jq) {
            int n = n0 + jq * 64 + tx * 4;
            float4 v;
            v.x = acc[i][jq * 4 + 0] * 0.125f;
            v.y = acc[i][jq * 4 + 1] * 0.125f;
            v.z = acc[i][jq * 4 + 2] * 0.125f;
            v.w = acc[i][jq * 4 + 3] * 0.125f;
            *(float4*)&Cz[(size_t)m * Ss + n] = v;
        }
    }
}

// ---------------------------------------------------------------------------
// Per-row exact k-th-largest (radix select, 4x8-bit) + masked softmax.
// Row values stay in REGISTERS (8 per thread) for all passes; no sd[] array.
// Per-wave privatized histograms cut same-bin atomic serialization ~4x.
// grid = 65536 blocks x 256 threads.
// ---------------------------------------------------------------------------
__global__ __launch_bounds__(256) void topk_softmax_kernel(float* __restrict__ Sc) {
    const int tid = threadIdx.x;
    const int wv = tid >> 6;
    float* p = Sc + (size_t)blockIdx.x * Ss;

    __shared__ unsigned hist[4][256];
    __shared__ unsigned shist[256];
    __shared__ float red[256];
    __shared__ unsigned sel[2];

    // row into registers: thread t holds elements t, t+256, ..., t+1792
    float f[8];
    unsigned ubits[8];
#pragma unroll
    for (int j = 0; j < 8; ++j) {
        f[j] = p[tid + j * 256];
        ubits[j] = f2u(f[j]);
    }

    unsigned prefix = 0, rk = KSEL;
    for (int pass = 0; pass < 4; ++pass) {
        const int shift = 24 - pass * 8;
        hist[0][tid] = 0; hist[1][tid] = 0; hist[2][tid] = 0; hist[3][tid] = 0;
        __syncthreads();
#pragma unroll
        for (int j = 0; j < 8; ++j) {
            unsigned u = ubits[j];
            bool ok = (pass == 0) ? true : ((u >> (shift + 8)) == prefix);
            if (ok) atomicAdd(&hist[wv][(u >> shift) & 255u], 1u);
        }
        __syncthreads();
        shist[tid] = hist[0][tid] + hist[1][tid] + hist[2][tid] + hist[3][tid];
        __syncthreads();
        // inclusive suffix sum over 256 bins
        for (int off = 1; off < 256; off <<= 1) {
            unsigned a = shist[tid];
            unsigned b = (tid + off < 256) ? shist[tid + off] : 0u;
            __syncthreads();
            shist[tid] = a + b;
            __syncthreads();
        }
        unsigned Sn = (tid < 255) ? shist[tid + 1] : 0u;
        if (shist[tid] >= rk && Sn < rk) { sel[0] = (unsigned)tid; sel[1] = rk - Sn; }
        __syncthreads();
        prefix = (prefix << 8) | sel[0];
        rk = sel[1];
        __syncthreads();
    }
    const unsigned uth = prefix;   // exact bits of k-th largest score

    // row max (from registers)
    float lm = -INFINITY;
#pragma unroll
    for (int j = 0; j < 8; ++j) lm = fmaxf(lm, f[j]);
    red[tid] = lm;
    __syncthreads();
    for (int off = 128; off > 0; off >>= 1) {
        if (tid < off) red[tid] = fmaxf(red[tid], red[tid + off]);
        __syncthreads();
    }
    const float mx = red[0];
    __syncthreads();

    // masked exp + sum (from registers)
    float e[8];
    float ls = 0.f;
#pragma unroll
    for (int j = 0; j < 8; ++j) {
        float ev = (ubits[j] >= uth) ? __expf(f[j] - mx) : 0.f;
        e[j] = ev;
        ls += ev;
    }
    red[tid] = ls;
    __syncthreads();
    for (int off = 128; off > 0; off >>= 1) {
        if (tid < off) red[tid] += red[tid + off];
        __syncthreads();
    }
    const float inv = 1.f / red[0];

#pragma unroll
    for (int j = 0; j < 8; ++j) p[tid + j * 256] = e[j] * inv;
}

// ---------------------------------------------------------------------------
// O_bh = attn_bh (2048x2048) @ V_bh (2048x64), written into O[B][S][D] layout.
// grid (16, 32). Tile 128(M) x 64(N), K-tile 32, microtile 8x4.
// ---------------------------------------------------------------------------
__global__ __launch_bounds__(256) void pv_kernel(const float* __restrict__ A,
                                                 const float* __restrict__ V,
                                                 float* __restrict__ O) {
    const int tid = threadIdx.x;
    const int tx = tid & 15, ty = tid >> 4;
    const int z = blockIdx.y;
    const int m0 = blockIdx.x * 128;
    const int bi = z >> 4, h = z & 15;
    const float* Az = A + (size_t)z * Ss * Ss;
    const float* Vz = V + (size_t)z * Ss * HDd;

    __shared__ __align__(16) float As[32][128];
    __shared__ __align__(16) float Bs[32][64];

    float acc[8][4];
#pragma unroll
    for (int i = 0; i < 8; ++i)
#pragma unroll
        for (int j = 0; j < 4; ++j) acc[i][j] = 0.f;

    for (int k0 = 0; k0 < Ss; k0 += 32) {
#pragma unroll
        for (int c = 0; c < 4; ++c) {
            int idx = tid + c * 256;
            int row = idx >> 3;
            int kq  = (idx & 7) << 2;
            float4 va = *(const float4*)&Az[(size_t)(m0 + row) * Ss + k0 + kq];
            As[kq + 0][row] = va.x; As[kq + 1][row] = va.y;
            As[kq + 2][row] = va.z; As[kq + 3][row] = va.w;
        }
#pragma unroll
        for (int c = 0; c < 2; ++c) {
            int idx = tid + c * 256;
            int kr = idx >> 4;
            int dq = (idx & 15) << 2;
            *(float4*)&Bs[kr][dq] = *(const float4*)&Vz[(size_t)(k0 + kr) * 64 + dq];
        }
        __syncthreads();
#pragma unroll
        for (int kk = 0; kk < 32; ++kk) {
            float a[8], b[4];
            *(float4*)&a[0] = *(const float4*)&As[kk][ty * 8];
            *(float4*)&a[4] = *(const float4*)&As[kk][ty * 8 + 4];
            *(float4*)&b[0] = *(const float4*)&Bs[kk][tx * 4];
#pragma unroll
            for (int i = 0; i < 8; ++i)
#pragma unroll
                for (int j = 0; j < 4; ++j) acc[i][j] = fmaf(a[i], b[j], acc[i][j]);
        }
        __syncthreads();
    }

#pragma unroll
    for (int i = 0; i < 8; ++i) {
        int srow = m0 + ty * 8 + i;
        float4 v = {acc[i][0], acc[i][1], acc[i][2], acc[i][3]};
        *(float4*)&O[((size_t)(bi * Ss + srow)) * Dd + h * 64 + tx * 4] = v;
    }
}

// ---------------------------------------------------------------------------
extern "C" void kernel_launch(void* const* d_in, const int* in_sizes, int n_in,
                              void* d_out, int out_size, void* d_ws, size_t ws_size,
                              hipStream_t stream) {
    const float* q  = (const float*)d_in[0];
    const float* k  = (const float*)d_in[1];
    const float* v  = (const float*)d_in[2];
    const float* Wq = (const float*)d_in[3];
    const float* bq = (const float*)d_in[4];
    const float* Wk = (const float*)d_in[5];
    const float* bk = (const float*)d_in[6];
    const float* Wv = (const float*)d_in[7];
    const float* bv = (const float*)d_in[8];
    const float* Wo = (const float*)d_in[9];
    const float* bo = (const float*)d_in[10];

    float* out  = (float*)d_out;                       // [B][S][D]
    float* attn = out + (size_t)Bb * Ss * Dd;          // [B][H][S][S] (scores scratch -> attn)

    float* ws = (float*)d_ws;
    const size_t SZ = (size_t)Bb * Ss * Dd;            // 4194304
    float* Qb = ws;
    float* Kb = ws + SZ;
    float* Vb = ws + 2 * SZ;
    float* Ob = ws + 3 * SZ;

    dim3 blk(256);

    qkv_kernel<<<dim3(8, 32, 3), blk, 0, stream>>>(q, k, v, Wq, Wk, Wv, bq, bk, bv, Qb, Kb, Vb);
    scores_kernel<<<dim3(16, 16, 32), blk, 0, stream>>>(Qb, Kb, attn);
    topk_softmax_kernel<<<dim3(65536), blk, 0, stream>>>(attn);
    pv_kernel<<<dim3(16, 32), blk, 0, stream>>>(attn, Vb, Ob);
    outproj_kernel<<<dim3(8, 32), blk, 0, stream>>>(Ob, Wo, bo, out);
}

// Round 5
// 1707.336 us; speedup vs baseline: 1.0362x; 1.0362x over previous
//
#include <hip/hip_runtime.h>
#include <math.h>

#define Bb 2
#define Ss 2048
#define Dd 1024
#define Hh 16
#define HDd 64
#define KSEL 1024           // k = S * (1 - 0.5)
#define MROWS 4096          // B*S

__device__ __forceinline__ unsigned f2u(float f) {
    unsigned u = __float_as_uint(f);
    return (u & 0x80000000u) ? ~u : (u | 0x80000000u);
}

// ---------------------------------------------------------------------------
// GEMM body: C(128x128) tile of  Y = X @ W^T (+bias), X: Mx1024, W: 1024x1024
// 256 threads, 8x8 microtile. TRANSPOSED=1 writes Y as [B][H][S][HD].
// ---------------------------------------------------------------------------
template <int TRANSPOSED>
__device__ __forceinline__ void gemm_body_1024(const float* __restrict__ X,
                                               const float* __restrict__ W,
                                               const float* __restrict__ bias,
                                               float* __restrict__ Y,
                                               int m0, int n0) {
    const int tid = threadIdx.x;
    const int tx = tid & 15, ty = tid >> 4;

    __shared__ __align__(16) float As[16][128];
    __shared__ __align__(16) float Bs[16][128];

    float acc[8][8];
#pragma unroll
    for (int i = 0; i < 8; ++i)
#pragma unroll
        for (int j = 0; j < 8; ++j) acc[i][j] = 0.f;

    for (int k0 = 0; k0 < 1024; k0 += 16) {
#pragma unroll
        for (int c = 0; c < 2; ++c) {
            int idx = tid + c * 256;
            int row = idx >> 2;
            int kq  = (idx & 3) << 2;
            float4 va = *(const float4*)&X[(size_t)(m0 + row) * 1024 + k0 + kq];
            As[kq + 0][row] = va.x; As[kq + 1][row] = va.y;
            As[kq + 2][row] = va.z; As[kq + 3][row] = va.w;
            float4 vb = *(const float4*)&W[(size_t)(n0 + row) * 1024 + k0 + kq];
            Bs[kq + 0][row] = vb.x; Bs[kq + 1][row] = vb.y;
            Bs[kq + 2][row] = vb.z; Bs[kq + 3][row] = vb.w;
        }
        __syncthreads();
#pragma unroll
        for (int kk = 0; kk < 16; ++kk) {
            float a[8], b[8];
            *(float4*)&a[0] = *(const float4*)&As[kk][ty * 4];
            *(float4*)&a[4] = *(const float4*)&As[kk][64 + ty * 4];
            *(float4*)&b[0] = *(const float4*)&Bs[kk][tx * 4];
            *(float4*)&b[4] = *(const float4*)&Bs[kk][64 + tx * 4];
#pragma unroll
            for (int i = 0; i < 8; ++i)
#pragma unroll
                for (int j = 0; j < 8; ++j) acc[i][j] = fmaf(a[i], b[j], acc[i][j]);
        }
        __syncthreads();
    }

#pragma unroll
    for (int i = 0; i < 8; ++i) {
        int m = m0 + ((i < 4) ? (ty * 4 + i) : (64 + ty * 4 + i - 4));
#pragma unroll
        for (int jq = 0; jq < 2; ++jq) {
            int n = n0 + jq * 64 + tx * 4;
            float4 bv = *(const float4*)&bias[n];
            float4 v;
            v.x = acc[i][jq * 4 + 0] + bv.x;
            v.y = acc[i][jq * 4 + 1] + bv.y;
            v.z = acc[i][jq * 4 + 2] + bv.z;
            v.w = acc[i][jq * 4 + 3] + bv.w;
            if (TRANSPOSED) {
                int bi = m >> 11, s = m & 2047;
                int h = n >> 6, d = n & 63;
                *(float4*)&Y[(((size_t)(bi * Hh + h)) * Ss + s) * HDd + d] = v;
            } else {
                *(float4*)&Y[(size_t)m * 1024 + n] = v;
            }
        }
    }
}

// QKV fused: grid (N/128=8, M/128=32, 3)
__global__ __launch_bounds__(256) void qkv_kernel(
    const float* __restrict__ q, const float* __restrict__ k, const float* __restrict__ v,
    const float* __restrict__ Wq, const float* __restrict__ Wk, const float* __restrict__ Wv,
    const float* __restrict__ bq, const float* __restrict__ bk, const float* __restrict__ bv,
    float* __restrict__ Qo, float* __restrict__ Ko, float* __restrict__ Vo) {
    int z = blockIdx.z;
    const float* X = (z == 0) ? q : ((z == 1) ? k : v);
    const float* W = (z == 0) ? Wq : ((z == 1) ? Wk : Wv);
    const float* bias = (z == 0) ? bq : ((z == 1) ? bk : bv);
    float* Y = (z == 0) ? Qo : ((z == 1) ? Ko : Vo);
    gemm_body_1024<1>(X, W, bias, Y, blockIdx.y * 128, blockIdx.x * 128);
}

// out = O @ Wo^T + bo : grid (8, 32)
__global__ __launch_bounds__(256) void outproj_kernel(
    const float* __restrict__ O, const float* __restrict__ Wo,
    const float* __restrict__ bo, float* __restrict__ Y) {
    gemm_body_1024<0>(O, Wo, bo, Y, blockIdx.y * 128, blockIdx.x * 128);
}

// ---------------------------------------------------------------------------
// scores = Q_bh @ K_bh^T * 0.125 : grid (16, 16, 32), K-dim = 64
// ---------------------------------------------------------------------------
__global__ __launch_bounds__(256) void scores_kernel(const float* __restrict__ Q,
                                                     const float* __restrict__ Kd,
                                                     float* __restrict__ Sc) {
    const int tid = threadIdx.x;
    const int tx = tid & 15, ty = tid >> 4;
    const int z = blockIdx.z;
    const int m0 = blockIdx.y * 128;
    const int n0 = blockIdx.x * 128;
    const float* Qz = Q + (size_t)z * Ss * HDd;
    const float* Kz = Kd + (size_t)z * Ss * HDd;
    float* Cz = Sc + (size_t)z * Ss * Ss;

    __shared__ __align__(16) float As[16][128];
    __shared__ __align__(16) float Bs[16][128];

    float acc[8][8];
#pragma unroll
    for (int i = 0; i < 8; ++i)
#pragma unroll
        for (int j = 0; j < 8; ++j) acc[i][j] = 0.f;

    for (int k0 = 0; k0 < 64; k0 += 16) {
#pragma unroll
        for (int c = 0; c < 2; ++c) {
            int idx = tid + c * 256;
            int row = idx >> 2;
            int kq  = (idx & 3) << 2;
            float4 va = *(const float4*)&Qz[(size_t)(m0 + row) * 64 + k0 + kq];
            As[kq + 0][row] = va.x; As[kq + 1][row] = va.y;
            As[kq + 2][row] = va.z; As[kq + 3][row] = va.w;
            float4 vb = *(const float4*)&Kz[(size_t)(n0 + row) * 64 + k0 + kq];
            Bs[kq + 0][row] = vb.x; Bs[kq + 1][row] = vb.y;
            Bs[kq + 2][row] = vb.z; Bs[kq + 3][row] = vb.w;
        }
        __syncthreads();
#pragma unroll
        for (int kk = 0; kk < 16; ++kk) {
            float a[8], b[8];
            *(float4*)&a[0] = *(const float4*)&As[kk][ty * 4];
            *(float4*)&a[4] = *(const float4*)&As[kk][64 + ty * 4];
            *(float4*)&b[0] = *(const float4*)&Bs[kk][tx * 4];
            *(float4*)&b[4] = *(const float4*)&Bs[kk][64 + tx * 4];
#pragma unroll
            for (int i = 0; i < 8; ++i)
#pragma unroll
                for (int j = 0; j < 8; ++j) acc[i][j] = fmaf(a[i], b[j], acc[i][j]);
        }
        __syncthreads();
    }

#pragma unroll
    for (int i = 0; i < 8; ++i) {
        int m = m0 + ((i < 4) ? (ty * 4 + i) : (64 + ty * 4 + i - 4));
#pragma unroll
        for (int jq = 0; jq < 2; ++jq) {
            int n = n0 + jq * 64 + tx * 4;
            float4 v;
            v.x = acc[i][jq * 4 + 0] * 0.125f;
            v.y = acc[i][jq * 4 + 1] * 0.125f;
            v.z = acc[i][jq * 4 + 2] * 0.125f;
            v.w = acc[i][jq * 4 + 3] * 0.125f;
            *(float4*)&Cz[(size_t)m * Ss + n] = v;
        }
    }
}

// ---------------------------------------------------------------------------
// Per-row exact k-th-largest (radix select, 4x8-bit) + masked softmax.
// Same construct set as the proven kernel (LDS + atomicAdd + syncthreads).
// Changes vs proven version:
//  - hierarchical crossing-bin search (16 group sums + serial scan by t0)
//    instead of the 16-barrier Hillis-Steele suffix scan (4 barriers/pass)
//  - 8 lane-parity-split histograms, rows padded +4 so rows land on
//    different LDS banks (halves same-bin atomic serialization)
//  - 3-barrier max/sum reductions instead of 8-step trees
// grid = 65536 blocks x 256 threads.
// ---------------------------------------------------------------------------
__global__ __launch_bounds__(256) void topk_softmax_kernel(float* __restrict__ Sc) {
    const int tid = threadIdx.x;
    const int hrow = ((tid >> 6) << 1) | (tid & 1);   // 8 privatized rows
    float* p = Sc + (size_t)blockIdx.x * Ss;

    __shared__ unsigned hist[8][260];
    __shared__ unsigned shist[256];
    __shared__ unsigned gs[16];
    __shared__ float red[256];
    __shared__ unsigned sel[2];
    __shared__ float fred[2];

    // row into registers: thread t holds elements t, t+256, ..., t+1792
    float f[8];
    unsigned ubits[8];
#pragma unroll
    for (int j = 0; j < 8; ++j) {
        f[j] = p[tid + j * 256];
        ubits[j] = f2u(f[j]);
    }

    unsigned prefix = 0, rk = KSEL;
    for (int pass = 0; pass < 4; ++pass) {
        const int shift = 24 - pass * 8;
        for (int i = tid; i < 8 * 260; i += 256) (&hist[0][0])[i] = 0u;
        __syncthreads();
#pragma unroll
        for (int j = 0; j < 8; ++j) {
            unsigned u = ubits[j];
            bool ok = (pass == 0) ? true : ((u >> (shift + 8)) == prefix);
            if (ok) atomicAdd(&hist[hrow][(u >> shift) & 255u], 1u);
        }
        __syncthreads();
        unsigned bc = 0;
#pragma unroll
        for (int r = 0; r < 8; ++r) bc += hist[r][tid];
        shist[tid] = bc;
        __syncthreads();
        if (tid < 16) {
            unsigned s = 0;
            for (int i = 0; i < 16; ++i) s += shist[tid * 16 + i];
            gs[tid] = s;
        }
        __syncthreads();
        if (tid == 0) {
            // find group containing the rk-th largest, scanning from top
            unsigned run = 0;
            int g = 15;
            for (; g > 0; --g) {
                unsigned c = gs[g];
                if (run + c >= rk) break;
                run += c;
            }
            unsigned need = rk - run;
            // find bin within group g, scanning from top
            unsigned run2 = 0;
            int b = g * 16 + 15;
            for (; b > g * 16; --b) {
                unsigned c = shist[b];
                if (run2 + c >= need) break;
                run2 += c;
            }
            sel[0] = (unsigned)b;
            sel[1] = need - run2;
        }
        __syncthreads();
        prefix = (prefix << 8) | sel[0];
        rk = sel[1];
    }
    const unsigned uth = prefix;   // exact bits of k-th largest score

    // row max: lane-local, then 32-wide stage, then serial by t0
    float lm = -INFINITY;
#pragma unroll
    for (int j = 0; j < 8; ++j) lm = fmaxf(lm, f[j]);
    red[tid] = lm;
    __syncthreads();
    if (tid < 32) {
        float m = red[tid];
#pragma unroll
        for (int i = 1; i < 8; ++i) m = fmaxf(m, red[tid + 32 * i]);
        red[tid] = m;
    }
    __syncthreads();
    if (tid == 0) {
        float m = red[0];
        for (int i = 1; i < 32; ++i) m = fmaxf(m, red[i]);
        fred[0] = m;
    }
    __syncthreads();
    const float mx = fred[0];

    // masked exp + sum
    float e[8];
    float ls = 0.f;
#pragma unroll
    for (int j = 0; j < 8; ++j) {
        float ev = (ubits[j] >= uth) ? __expf(f[j] - mx) : 0.f;
        e[j] = ev;
        ls += ev;
    }
    red[tid] = ls;
    __syncthreads();
    if (tid < 32) {
        float s2 = red[tid];
#pragma unroll
        for (int i = 1; i < 8; ++i) s2 += red[tid + 32 * i];
        red[tid] = s2;
    }
    __syncthreads();
    if (tid == 0) {
        float s2 = red[0];
        for (int i = 1; i < 32; ++i) s2 += red[i];
        fred[1] = s2;
    }
    __syncthreads();
    const float inv = 1.f / fred[1];

#pragma unroll
    for (int j = 0; j < 8; ++j) p[tid + j * 256] = e[j] * inv;
}

// ---------------------------------------------------------------------------
// O_bh = attn_bh (2048x2048) @ V_bh (2048x64), written into O[B][S][D] layout.
// grid (16, 32). Tile 128(M) x 64(N), K-tile 32, microtile 8x4.
// ---------------------------------------------------------------------------
__global__ __launch_bounds__(256) void pv_kernel(const float* __restrict__ A,
                                                 const float* __restrict__ V,
                                                 float* __restrict__ O) {
    const int tid = threadIdx.x;
    const int tx = tid & 15, ty = tid >> 4;
    const int z = blockIdx.y;
    const int m0 = blockIdx.x * 128;
    const int bi = z >> 4, h = z & 15;
    const float* Az = A + (size_t)z * Ss * Ss;
    const float* Vz = V + (size_t)z * Ss * HDd;

    __shared__ __align__(16) float As[32][128];
    __shared__ __align__(16) float Bs[32][64];

    float acc[8][4];
#pragma unroll
    for (int i = 0; i < 8; ++i)
#pragma unroll
        for (int j = 0; j < 4; ++j) acc[i][j] = 0.f;

    for (int k0 = 0; k0 < Ss; k0 += 32) {
#pragma unroll
        for (int c = 0; c < 4; ++c) {
            int idx = tid + c * 256;
            int row = idx >> 3;
            int kq  = (idx & 7) << 2;
            float4 va = *(const float4*)&Az[(size_t)(m0 + row) * Ss + k0 + kq];
            As[kq + 0][row] = va.x; As[kq + 1][row] = va.y;
            As[kq + 2][row] = va.z; As[kq + 3][row] = va.w;
        }
#pragma unroll
        for (int c = 0; c < 2; ++c) {
            int idx = tid + c * 256;
            int kr = idx >> 4;
            int dq = (idx & 15) << 2;
            *(float4*)&Bs[kr][dq] = *(const float4*)&Vz[(size_t)(k0 + kr) * 64 + dq];
        }
        __syncthreads();
#pragma unroll
        for (int kk = 0; kk < 32; ++kk) {
            float a[8], b[4];
            *(float4*)&a[0] = *(const float4*)&As[kk][ty * 8];
            *(float4*)&a[4] = *(const float4*)&As[kk][ty * 8 + 4];
            *(float4*)&b[0] = *(const float4*)&Bs[kk][tx * 4];
#pragma unroll
            for (int i = 0; i < 8; ++i)
#pragma unroll
                for (int j = 0; j < 4; ++j) acc[i][j] = fmaf(a[i], b[j], acc[i][j]);
        }
        __syncthreads();
    }

#pragma unroll
    for (int i = 0; i < 8; ++i) {
        int srow = m0 + ty * 8 + i;
        float4 v = {acc[i][0], acc[i][1], acc[i][2], acc[i][3]};
        *(float4*)&O[((size_t)(bi * Ss + srow)) * Dd + h * 64 + tx * 4] = v;
    }
}

// ---------------------------------------------------------------------------
extern "C" void kernel_launch(void* const* d_in, const int* in_sizes, int n_in,
                              void* d_out, int out_size, void* d_ws, size_t ws_size,
                              hipStream_t stream) {
    const float* q  = (const float*)d_in[0];
    const float* k  = (const float*)d_in[1];
    const float* v  = (const float*)d_in[2];
    const float* Wq = (const float*)d_in[3];
    const float* bq = (const float*)d_in[4];
    const float* Wk = (const float*)d_in[5];
    const float* bk = (const float*)d_in[6];
    const float* Wv = (const float*)d_in[7];
    const float* bv = (const float*)d_in[8];
    const float* Wo = (const float*)d_in[9];
    const float* bo = (const float*)d_in[10];

    float* out  = (float*)d_out;                       // [B][S][D]
    float* attn = out + (size_t)Bb * Ss * Dd;          // [B][H][S][S] (scores scratch -> attn)

    float* ws = (float*)d_ws;
    const size_t SZ = (size_t)Bb * Ss * Dd;            // 4194304
    float* Qb = ws;
    float* Kb = ws + SZ;
    float* Vb = ws + 2 * SZ;
    float* Ob = ws + 3 * SZ;

    dim3 blk(256);

    qkv_kernel<<<dim3(8, 32, 3), blk, 0, stream>>>(q, k, v, Wq, Wk, Wv, bq, bk, bv, Qb, Kb, Vb);
    scores_kernel<<<dim3(16, 16, 32), blk, 0, stream>>>(Qb, Kb, attn);
    topk_softmax_kernel<<<dim3(65536), blk, 0, stream>>>(attn);
    pv_kernel<<<dim3(16, 32), blk, 0, stream>>>(attn, Vb, Ob);
    outproj_kernel<<<dim3(8, 32), blk, 0, stream>>>(Ob, Wo, bo, out);
}

// Round 6
// 1672.168 us; speedup vs baseline: 1.0579x; 1.0210x over previous
//
#include <hip/hip_runtime.h>
#include <math.h>

#define Bb 2
#define Ss 2048
#define Dd 1024
#define Hh 16
#define HDd 64
#define KSEL 1024           // k = S * (1 - 0.5)
#define MROWS 4096          // B*S

__device__ __forceinline__ unsigned f2u(float f) {
    unsigned u = __float_as_uint(f);
    return (u & 0x80000000u) ? ~u : (u | 0x80000000u);
}

// ---------------------------------------------------------------------------
// GEMM body: C(128x128) tile of  Y = X @ W^T (+bias), X: Mx1024, W: 1024x1024
// 256 threads, 8x8 microtile. TRANSPOSED=1 writes Y as [B][H][S][HD].
// ---------------------------------------------------------------------------
template <int TRANSPOSED>
__device__ __forceinline__ void gemm_body_1024(const float* __restrict__ X,
                                               const float* __restrict__ W,
                                               const float* __restrict__ bias,
                                               float* __restrict__ Y,
                                               int m0, int n0) {
    const int tid = threadIdx.x;
    const int tx = tid & 15, ty = tid >> 4;

    __shared__ __align__(16) float As[16][128];
    __shared__ __align__(16) float Bs[16][128];

    float acc[8][8];
#pragma unroll
    for (int i = 0; i < 8; ++i)
#pragma unroll
        for (int j = 0; j < 8; ++j) acc[i][j] = 0.f;

    for (int k0 = 0; k0 < 1024; k0 += 16) {
#pragma unroll
        for (int c = 0; c < 2; ++c) {
            int idx = tid + c * 256;
            int row = idx >> 2;
            int kq  = (idx & 3) << 2;
            float4 va = *(const float4*)&X[(size_t)(m0 + row) * 1024 + k0 + kq];
            As[kq + 0][row] = va.x; As[kq + 1][row] = va.y;
            As[kq + 2][row] = va.z; As[kq + 3][row] = va.w;
            float4 vb = *(const float4*)&W[(size_t)(n0 + row) * 1024 + k0 + kq];
            Bs[kq + 0][row] = vb.x; Bs[kq + 1][row] = vb.y;
            Bs[kq + 2][row] = vb.z; Bs[kq + 3][row] = vb.w;
        }
        __syncthreads();
#pragma unroll
        for (int kk = 0; kk < 16; ++kk) {
            float a[8], b[8];
            *(float4*)&a[0] = *(const float4*)&As[kk][ty * 4];
            *(float4*)&a[4] = *(const float4*)&As[kk][64 + ty * 4];
            *(float4*)&b[0] = *(const float4*)&Bs[kk][tx * 4];
            *(float4*)&b[4] = *(const float4*)&Bs[kk][64 + tx * 4];
#pragma unroll
            for (int i = 0; i < 8; ++i)
#pragma unroll
                for (int j = 0; j < 8; ++j) acc[i][j] = fmaf(a[i], b[j], acc[i][j]);
        }
        __syncthreads();
    }

#pragma unroll
    for (int i = 0; i < 8; ++i) {
        int m = m0 + ((i < 4) ? (ty * 4 + i) : (64 + ty * 4 + i - 4));
#pragma unroll
        for (int jq = 0; jq < 2; ++jq) {
            int n = n0 + jq * 64 + tx * 4;
            float4 bv = *(const float4*)&bias[n];
            float4 v;
            v.x = acc[i][jq * 4 + 0] + bv.x;
            v.y = acc[i][jq * 4 + 1] + bv.y;
            v.z = acc[i][jq * 4 + 2] + bv.z;
            v.w = acc[i][jq * 4 + 3] + bv.w;
            if (TRANSPOSED) {
                int bi = m >> 11, s = m & 2047;
                int h = n >> 6, d = n & 63;
                *(float4*)&Y[(((size_t)(bi * Hh + h)) * Ss + s) * HDd + d] = v;
            } else {
                *(float4*)&Y[(size_t)m * 1024 + n] = v;
            }
        }
    }
}

// QKV fused: grid (N/128=8, M/128=32, 3)
__global__ __launch_bounds__(256) void qkv_kernel(
    const float* __restrict__ q, const float* __restrict__ k, const float* __restrict__ v,
    const float* __restrict__ Wq, const float* __restrict__ Wk, const float* __restrict__ Wv,
    const float* __restrict__ bq, const float* __restrict__ bk, const float* __restrict__ bv,
    float* __restrict__ Qo, float* __restrict__ Ko, float* __restrict__ Vo) {
    int z = blockIdx.z;
    const float* X = (z == 0) ? q : ((z == 1) ? k : v);
    const float* W = (z == 0) ? Wq : ((z == 1) ? Wk : Wv);
    const float* bias = (z == 0) ? bq : ((z == 1) ? bk : bv);
    float* Y = (z == 0) ? Qo : ((z == 1) ? Ko : Vo);
    gemm_body_1024<1>(X, W, bias, Y, blockIdx.y * 128, blockIdx.x * 128);
}

// out = O @ Wo^T + bo : grid (8, 32)
__global__ __launch_bounds__(256) void outproj_kernel(
    const float* __restrict__ O, const float* __restrict__ Wo,
    const float* __restrict__ bo, float* __restrict__ Y) {
    gemm_body_1024<0>(O, Wo, bo, Y, blockIdx.y * 128, blockIdx.x * 128);
}

// ---------------------------------------------------------------------------
// scores = Q_bh @ K_bh^T * 0.125 : grid (16, 16, 32), K-dim = 64
// ---------------------------------------------------------------------------
__global__ __launch_bounds__(256) void scores_kernel(const float* __restrict__ Q,
                                                     const float* __restrict__ Kd,
                                                     float* __restrict__ Sc) {
    const int tid = threadIdx.x;
    const int tx = tid & 15, ty = tid >> 4;
    const int z = blockIdx.z;
    const int m0 = blockIdx.y * 128;
    const int n0 = blockIdx.x * 128;
    const float* Qz = Q + (size_t)z * Ss * HDd;
    const float* Kz = Kd + (size_t)z * Ss * HDd;
    float* Cz = Sc + (size_t)z * Ss * Ss;

    __shared__ __align__(16) float As[16][128];
    __shared__ __align__(16) float Bs[16][128];

    float acc[8][8];
#pragma unroll
    for (int i = 0; i < 8; ++i)
#pragma unroll
        for (int j = 0; j < 8; ++j) acc[i][j] = 0.f;

    for (int k0 = 0; k0 < 64; k0 += 16) {
#pragma unroll
        for (int c = 0; c < 2; ++c) {
            int idx = tid + c * 256;
            int row = idx >> 2;
            int kq  = (idx & 3) << 2;
            float4 va = *(const float4*)&Qz[(size_t)(m0 + row) * 64 + k0 + kq];
            As[kq + 0][row] = va.x; As[kq + 1][row] = va.y;
            As[kq + 2][row] = va.z; As[kq + 3][row] = va.w;
            float4 vb = *(const float4*)&Kz[(size_t)(n0 + row) * 64 + k0 + kq];
            Bs[kq + 0][row] = vb.x; Bs[kq + 1][row] = vb.y;
            Bs[kq + 2][row] = vb.z; Bs[kq + 3][row] = vb.w;
        }
        __syncthreads();
#pragma unroll
        for (int kk = 0; kk < 16; ++kk) {
            float a[8], b[8];
            *(float4*)&a[0] = *(const float4*)&As[kk][ty * 4];
            *(float4*)&a[4] = *(const float4*)&As[kk][64 + ty * 4];
            *(float4*)&b[0] = *(const float4*)&Bs[kk][tx * 4];
            *(float4*)&b[4] = *(const float4*)&Bs[kk][64 + tx * 4];
#pragma unroll
            for (int i = 0; i < 8; ++i)
#pragma unroll
                for (int j = 0; j < 8; ++j) acc[i][j] = fmaf(a[i], b[j], acc[i][j]);
        }
        __syncthreads();
    }

#pragma unroll
    for (int i = 0; i < 8; ++i) {
        int m = m0 + ((i < 4) ? (ty * 4 + i) : (64 + ty * 4 + i - 4));
#pragma unroll
        for (int jq = 0; jq < 2; ++jq) {
            int n = n0 + jq * 64 + tx * 4;
            float4 v;
            v.x = acc[i][jq * 4 + 0] * 0.125f;
            v.y = acc[i][jq * 4 + 1] * 0.125f;
            v.z = acc[i][jq * 4 + 2] * 0.125f;
            v.w = acc[i][jq * 4 + 3] * 0.125f;
            *(float4*)&Cz[(size_t)m * Ss + n] = v;
        }
    }
}

// ---------------------------------------------------------------------------
// Per-row exact k-th-largest + masked softmax, in place.
// 3-pass radix select (12+10+10 bits) on order-preserving f2u bits.
// Single histogram copy (12-bit pass spreads scores over ~140 bins, so
// same-address atomic collisions are ~3-way: no privatization needed).
// uint4-vectorized LDS clear/read; hierarchical crossing search.
// Same construct set as the proven kernel (LDS + atomicAdd + syncthreads).
// grid = 65536 blocks x 256 threads.
// ---------------------------------------------------------------------------
__global__ __launch_bounds__(256) void topk_softmax_kernel(float* __restrict__ Sc) {
    const int tid = threadIdx.x;
    float* p = Sc + (size_t)blockIdx.x * Ss;

    __shared__ __align__(16) unsigned hist[4096];
    __shared__ unsigned gs[256];
    __shared__ unsigned ggs[16];
    __shared__ float red[256];
    __shared__ unsigned sel[2];
    __shared__ float fred[2];

    // row into registers, vectorized: thread t holds elements
    // [4t..4t+3] and [1024+4t..1024+4t+3] (mapping is irrelevant to
    // row-wide selection/reduction; write-back uses the same addresses)
    float f[8];
    unsigned ubits[8];
    {
        float4 a = *(const float4*)&p[tid * 4];
        float4 b = *(const float4*)&p[1024 + tid * 4];
        f[0] = a.x; f[1] = a.y; f[2] = a.z; f[3] = a.w;
        f[4] = b.x; f[5] = b.y; f[6] = b.z; f[7] = b.w;
    }
#pragma unroll
    for (int j = 0; j < 8; ++j) ubits[j] = f2u(f[j]);

    unsigned rk = KSEL;
    unsigned prefix = 0;

    uint4 zz; zz.x = 0u; zz.y = 0u; zz.z = 0u; zz.w = 0u;

    // ---------------- pass 0: top 12 bits, 4096 bins ----------------
    {
#pragma unroll
        for (int q = 0; q < 4; ++q) *(uint4*)&hist[tid * 16 + q * 4] = zz;
        __syncthreads();
#pragma unroll
        for (int j = 0; j < 8; ++j) atomicAdd(&hist[ubits[j] >> 20], 1u);
        __syncthreads();
        unsigned s = 0;
#pragma unroll
        for (int q = 0; q < 4; ++q) {
            uint4 hv = *(const uint4*)&hist[tid * 16 + q * 4];
            s += hv.x + hv.y + hv.z + hv.w;
        }
        gs[tid] = s;                       // gs[t] = bins [16t, 16t+16)
        __syncthreads();
        if (tid < 16) {
            unsigned t2 = 0;
            for (int i = 0; i < 16; ++i) t2 += gs[tid * 16 + i];
            ggs[tid] = t2;                 // ggs[g] = bins [256g, 256g+256)
        }
        __syncthreads();
        if (tid == 0) {
            unsigned run = 0;
            int g = 15;
            for (; g > 0; --g) { unsigned c = ggs[g]; if (run + c >= rk) break; run += c; }
            int sg = g * 16 + 15;
            for (; sg > g * 16; --sg) { unsigned c = gs[sg]; if (run + c >= rk) break; run += c; }
            int b = sg * 16 + 15;
            for (; b > sg * 16; --b) { unsigned c = hist[b]; if (run + c >= rk) break; run += c; }
            sel[0] = (unsigned)b; sel[1] = rk - run;
        }
        __syncthreads();
        prefix = sel[0];                   // 12 bits
        rk = sel[1];
    }

    // ---------------- pass 1: next 10 bits, 1024 bins ----------------
    {
        *(uint4*)&hist[tid * 4] = zz;
        __syncthreads();
#pragma unroll
        for (int j = 0; j < 8; ++j) {
            if ((ubits[j] >> 20) == prefix)
                atomicAdd(&hist[(ubits[j] >> 10) & 1023u], 1u);
        }
        __syncthreads();
        {
            uint4 hv = *(const uint4*)&hist[tid * 4];
            gs[tid] = hv.x + hv.y + hv.z + hv.w;   // gs[t] = bins [4t, 4t+4)
        }
        __syncthreads();
        if (tid < 16) {
            unsigned t2 = 0;
            for (int i = 0; i < 16; ++i) t2 += gs[tid * 16 + i];
            ggs[tid] = t2;                 // ggs[g] = bins [64g, 64g+64)
        }
        __syncthreads();
        if (tid == 0) {
            unsigned run = 0;
            int g = 15;
            for (; g > 0; --g) { unsigned c = ggs[g]; if (run + c >= rk) break; run += c; }
            int sg = g * 16 + 15;
            for (; sg > g * 16; --sg) { unsigned c = gs[sg]; if (run + c >= rk) break; run += c; }
            int b = sg * 4 + 3;
            for (; b > sg * 4; --b) { unsigned c = hist[b]; if (run + c >= rk) break; run += c; }
            sel[0] = (unsigned)b; sel[1] = rk - run;
        }
        __syncthreads();
        prefix = (prefix << 10) | sel[0];  // 22 bits
        rk = sel[1];
    }

    // ---------------- pass 2: last 10 bits, 1024 bins ----------------
    {
        *(uint4*)&hist[tid * 4] = zz;
        __syncthreads();
#pragma unroll
        for (int j = 0; j < 8; ++j) {
            if ((ubits[j] >> 10) == prefix)
                atomicAdd(&hist[ubits[j] & 1023u], 1u);
        }
        __syncthreads();
        {
            uint4 hv = *(const uint4*)&hist[tid * 4];
            gs[tid] = hv.x + hv.y + hv.z + hv.w;
        }
        __syncthreads();
        if (tid < 16) {
            unsigned t2 = 0;
            for (int i = 0; i < 16; ++i) t2 += gs[tid * 16 + i];
            ggs[tid] = t2;
        }
        __syncthreads();
        if (tid == 0) {
            unsigned run = 0;
            int g = 15;
            for (; g > 0; --g) { unsigned c = ggs[g]; if (run + c >= rk) break; run += c; }
            int sg = g * 16 + 15;
            for (; sg > g * 16; --sg) { unsigned c = gs[sg]; if (run + c >= rk) break; run += c; }
            int b = sg * 4 + 3;
            for (; b > sg * 4; --b) { unsigned c = hist[b]; if (run + c >= rk) break; run += c; }
            sel[0] = (unsigned)b;
        }
        __syncthreads();
        prefix = (prefix << 10) | sel[0];  // full 32 bits
    }
    const unsigned uth = prefix;   // exact bits of k-th largest score

    // row max: lane-local, then 32-wide stage, then serial by t0
    float lm = -INFINITY;
#pragma unroll
    for (int j = 0; j < 8; ++j) lm = fmaxf(lm, f[j]);
    red[tid] = lm;
    __syncthreads();
    if (tid < 32) {
        float m = red[tid];
#pragma unroll
        for (int i = 1; i < 8; ++i) m = fmaxf(m, red[tid + 32 * i]);
        red[tid] = m;
    }
    __syncthreads();
    if (tid == 0) {
        float m = red[0];
        for (int i = 1; i < 32; ++i) m = fmaxf(m, red[i]);
        fred[0] = m;
    }
    __syncthreads();
    const float mx = fred[0];

    // masked exp + sum
    float e[8];
    float ls = 0.f;
#pragma unroll
    for (int j = 0; j < 8; ++j) {
        float ev = (ubits[j] >= uth) ? __expf(f[j] - mx) : 0.f;
        e[j] = ev;
        ls += ev;
    }
    red[tid] = ls;
    __syncthreads();
    if (tid < 32) {
        float s2 = red[tid];
#pragma unroll
        for (int i = 1; i < 8; ++i) s2 += red[tid + 32 * i];
        red[tid] = s2;
    }
    __syncthreads();
    if (tid == 0) {
        float s2 = red[0];
        for (int i = 1; i < 32; ++i) s2 += red[i];
        fred[1] = s2;
    }
    __syncthreads();
    const float inv = 1.f / fred[1];

    {
        float4 o;
        o.x = e[0] * inv; o.y = e[1] * inv; o.z = e[2] * inv; o.w = e[3] * inv;
        *(float4*)&p[tid * 4] = o;
        o.x = e[4] * inv; o.y = e[5] * inv; o.z = e[6] * inv; o.w = e[7] * inv;
        *(float4*)&p[1024 + tid * 4] = o;
    }
}

// ---------------------------------------------------------------------------
// O_bh = attn_bh (2048x2048) @ V_bh (2048x64), written into O[B][S][D] layout.
// grid (16, 32). Tile 128(M) x 64(N), K-tile 32, microtile 8x4.
// ---------------------------------------------------------------------------
__global__ __launch_bounds__(256) void pv_kernel(const float* __restrict__ A,
                                                 const float* __restrict__ V,
                                                 float* __restrict__ O) {
    const int tid = threadIdx.x;
    const int tx = tid & 15, ty = tid >> 4;
    const int z = blockIdx.y;
    const int m0 = blockIdx.x * 128;
    const int bi = z >> 4, h = z & 15;
    const float* Az = A + (size_t)z * Ss * Ss;
    const float* Vz = V + (size_t)z * Ss * HDd;

    __shared__ __align__(16) float As[32][128];
    __shared__ __align__(16) float Bs[32][64];

    float acc[8][4];
#pragma unroll
    for (int i = 0; i < 8; ++i)
#pragma unroll
        for (int j = 0; j < 4; ++j) acc[i][j] = 0.f;

    for (int k0 = 0; k0 < Ss; k0 += 32) {
#pragma unroll
        for (int c = 0; c < 4; ++c) {
            int idx = tid + c * 256;
            int row = idx >> 3;
            int kq  = (idx & 7) << 2;
            float4 va = *(const float4*)&Az[(size_t)(m0 + row) * Ss + k0 + kq];
            As[kq + 0][row] = va.x; As[kq + 1][row] = va.y;
            As[kq + 2][row] = va.z; As[kq + 3][row] = va.w;
        }
#pragma unroll
        for (int c = 0; c < 2; ++c) {
            int idx = tid + c * 256;
            int kr = idx >> 4;
            int dq = (idx & 15) << 2;
            *(float4*)&Bs[kr][dq] = *(const float4*)&Vz[(size_t)(k0 + kr) * 64 + dq];
        }
        __syncthreads();
#pragma unroll
        for (int kk = 0; kk < 32; ++kk) {
            float a[8], b[4];
            *(float4*)&a[0] = *(const float4*)&As[kk][ty * 8];
            *(float4*)&a[4] = *(const float4*)&As[kk][ty * 8 + 4];
            *(float4*)&b[0] = *(const float4*)&Bs[kk][tx * 4];
#pragma unroll
            for (int i = 0; i < 8; ++i)
#pragma unroll
                for (int j = 0; j < 4; ++j) acc[i][j] = fmaf(a[i], b[j], acc[i][j]);
        }
        __syncthreads();
    }

#pragma unroll
    for (int i = 0; i < 8; ++i) {
        int srow = m0 + ty * 8 + i;
        float4 v = {acc[i][0], acc[i][1], acc[i][2], acc[i][3]};
        *(float4*)&O[((size_t)(bi * Ss + srow)) * Dd + h * 64 + tx * 4] = v;
    }
}

// ---------------------------------------------------------------------------
extern "C" void kernel_launch(void* const* d_in, const int* in_sizes, int n_in,
                              void* d_out, int out_size, void* d_ws, size_t ws_size,
                              hipStream_t stream) {
    const float* q  = (const float*)d_in[0];
    const float* k  = (const float*)d_in[1];
    const float* v  = (const float*)d_in[2];
    const float* Wq = (const float*)d_in[3];
    const float* bq = (const float*)d_in[4];
    const float* Wk = (const float*)d_in[5];
    const float* bk = (const float*)d_in[6];
    const float* Wv = (const float*)d_in[7];
    const float* bv = (const float*)d_in[8];
    const float* Wo = (const float*)d_in[9];
    const float* bo = (const float*)d_in[10];

    float* out  = (float*)d_out;                       // [B][S][D]
    float* attn = out + (size_t)Bb * Ss * Dd;          // [B][H][S][S] (scores scratch -> attn)

    float* ws = (float*)d_ws;
    const size_t SZ = (size_t)Bb * Ss * Dd;            // 4194304
    float* Qb = ws;
    float* Kb = ws + SZ;
    float* Vb = ws + 2 * SZ;
    float* Ob = ws + 3 * SZ;

    dim3 blk(256);

    qkv_kernel<<<dim3(8, 32, 3), blk, 0, stream>>>(q, k, v, Wq, Wk, Wv, bq, bk, bv, Qb, Kb, Vb);
    scores_kernel<<<dim3(16, 16, 32), blk, 0, stream>>>(Qb, Kb, attn);
    topk_softmax_kernel<<<dim3(65536), blk, 0, stream>>>(attn);
    pv_kernel<<<dim3(16, 32), blk, 0, stream>>>(attn, Vb, Ob);
    outproj_kernel<<<dim3(8, 32), blk, 0, stream>>>(Ob, Wo, bo, out);
}